// Round 7
// baseline (178.693 us; speedup 1.0000x reference)
//
#include <hip/hip_runtime.h>

// Adaptive mean thresholding: out = (x > mean11x11(x) - 2) ? 0 : 255, replicate border.
// BIT-EXACT contract (verified absmax=0.0 in rounds 3-6): vertical 11-tap f32 FMA
// chain (ascending row order, weight (float)(1.0/11.0)), rounded to f32; then
// horizontal 11-tap f32 FMA chain (ascending col order); thresh = m - 2.0f;
// decision x > thresh. Replicate-border mv values are bitwise duplicates of the
// edge mv (synthesized by duplication, never recomputed).
//
// R7: R6 dataflow (wave-per-strip, 8 cols/lane, shuffle halo, no LDS/barriers)
// + explicit DEPTH-2 register prefetch: load for iteration k+2 issued at
//   iteration k -> ~600 cycles of own compute cover load latency, vmcnt never
//   drains (2 loads always in flight). R6 was 85% stalled (VALUBusy 14.6%).
// + XCD-contiguous block swizzle (1024 blocks, 128/XCD = 16 whole images per
//   XCD L2) so inter-block halo rows are L2 hits.
// + __launch_bounds__(256,4): cap VGPR at 128 to stay in the 4-waves/SIMD bucket.

constexpr int W   = 512;
constexpr int H   = 512;
constexpr int PAD = 5;
constexpr int KS  = 11;
constexpr int CPT = 8;           // columns per lane
constexpr int TPB = 256;         // 4 waves per block
constexpr int WPB = 4;           // waves (strips) per block
constexpr int RPB = 16;          // output rows per wave
constexpr int STRIPS = H / RPB;  // 32 strips per image
constexpr int NXCD = 8;

typedef float f32x4 __attribute__((ext_vector_type(4)));

__global__ __launch_bounds__(TPB, 4)
void AdaptiveThresholding_57904749085171_kernel(const float* __restrict__ x,
                                                float* __restrict__ out)
{
    const int l     = (int)threadIdx.x & 63;
    const int wv_id = (int)threadIdx.x >> 6;

    // XCD-contiguous swizzle: gridDim.x % 8 == 0 (1024), bijective.
    const int cpx = (int)gridDim.x / NXCD;
    const int bid = (int)blockIdx.x;
    const int swz = (bid % NXCD) * cpx + bid / NXCD;

    const int strip = swz * WPB + wv_id;
    const int img   = strip / STRIPS;
    const int y0    = (strip % STRIPS) * RPB;
    const size_t ioff = (size_t)img * (size_t)(W * H);
    const float* __restrict__ xi = x + ioff;
    float* __restrict__ oi = out + ioff;
    const int cbase = l * CPT;
    const float wv = (float)(1.0 / 11.0);

    float ring[KS][CPT];   // virtual rows y-5..y+5; slot s holds row r, (r-(y0-5))%11 == s
    float pf[2][CPT];      // depth-2 prefetch buffers (all indices static after unroll)

    // ---- prologue: virtual rows y0-5 .. y0+4 -> slots 0..9 (10 loads in flight) ----
    #pragma unroll
    for (int j = 0; j < KS - 1; ++j) {
        int row = y0 - PAD + j;
        row = row < 0 ? 0 : (row >= H ? H - 1 : row);
        const f32x4* p = (const f32x4*)(xi + (size_t)row * W + cbase);
        const f32x4 a = p[0], b = p[1];
        #pragma unroll
        for (int i = 0; i < 4; ++i) { ring[j][i] = a[i]; ring[j][4 + i] = b[i]; }
    }
    // prefetch rows for iterations 0 and 1 (virtual rows y0+5, y0+6)
    #pragma unroll
    for (int k = 0; k < 2; ++k) {
        int row = y0 + PAD + k;
        row = row >= H ? H - 1 : row;
        const f32x4* p = (const f32x4*)(xi + (size_t)row * W + cbase);
        const f32x4 a = p[0], b = p[1];
        #pragma unroll
        for (int i = 0; i < 4; ++i) { pf[k][i] = a[i]; pf[k][4 + i] = b[i]; }
    }

    #pragma unroll
    for (int k = 0; k < RPB; ++k) {
        // ---- consume prefetched row (tap d=10 of this iteration) into the ring ----
        #pragma unroll
        for (int i = 0; i < CPT; ++i) ring[(10 + k) % KS][i] = pf[k & 1][i];

        // ---- issue load for iteration k+2 into the buffer just freed ----
        if (k + 2 < RPB) {
            int row = y0 + PAD + k + 2;
            row = row >= H ? H - 1 : row;
            const f32x4* p = (const f32x4*)(xi + (size_t)row * W + cbase);
            const f32x4 a = p[0], b = p[1];
            #pragma unroll
            for (int i = 0; i < 4; ++i) { pf[k & 1][i] = a[i]; pf[k & 1][4 + i] = b[i]; }
        }

        // ---- vertical f32 FMA chains, ascending row order ----
        float a[CPT];
        #pragma unroll
        for (int i = 0; i < CPT; ++i) {
            float s = 0.0f;
            #pragma unroll
            for (int d = 0; d < KS; ++d) s = fmaf(ring[(k + d) % KS][i], wv, s);
            a[i] = s;
        }

        // ---- halo mv values from neighbor lanes (replicate at image edges) ----
        float zl[PAD], zr[PAD];
        #pragma unroll
        for (int q = 0; q < PAD; ++q) {
            const float vL = __shfl(a[3 + q], l - 1, 64);   // left lane cols 3..7
            zl[q] = (l == 0) ? a[0] : vL;                   // mv[<0] == mv[0] bitwise
            const float vR = __shfl(a[q], l + 1, 64);       // right lane cols 0..4
            zr[q] = (l == 63) ? a[7] : vR;                  // mv[>511] == mv[511]
        }

        // ---- horizontal f32 FMA chains (ascending col order) + decision ----
        float o[CPT];
        #pragma unroll
        for (int i = 0; i < CPT; ++i) {
            float m = 0.0f;
            #pragma unroll
            for (int d = 0; d < KS; ++d) {
                const int j = i + d;          // z[j], j in [i, i+10], z = [zl | a | zr]
                const float zv = (j < PAD) ? zl[j]
                               : (j < PAD + CPT) ? a[j - PAD]
                               : zr[j - PAD - CPT];
                m = fmaf(zv, wv, m);
            }
            const float xv = ring[(k + PAD) % KS][i];       // center row y value
            o[i] = (xv > m - 2.0f) ? 0.0f : 255.0f;
        }

        // ---- plain vector stores ----
        f32x4 o0, o1;
        #pragma unroll
        for (int i = 0; i < 4; ++i) { o0[i] = o[i]; o1[i] = o[4 + i]; }
        f32x4* op = (f32x4*)(oi + (size_t)(y0 + k) * W + cbase);
        op[0] = o0;
        op[1] = o1;
    }
}

extern "C" void kernel_launch(void* const* d_in, const int* in_sizes, int n_in,
                              void* d_out, int out_size, void* d_ws, size_t ws_size,
                              hipStream_t stream)
{
    const float* x = (const float*)d_in[0];
    float* out = (float*)d_out;
    const int n_imgs = in_sizes[0] / (W * H);   // 128
    const int n_strips = n_imgs * STRIPS;       // 4096

    dim3 grid(n_strips / WPB);   // 1024 blocks x 4 waves
    dim3 block(TPB);
    AdaptiveThresholding_57904749085171_kernel<<<grid, block, 0, stream>>>(x, out);
}

// Round 8
// 55.283 us; speedup vs baseline: 3.2324x; 3.2324x over previous
//
#include <hip/hip_runtime.h>

// Adaptive mean thresholding: out = (x > mean11x11(x) - 2) ? 0 : 255, replicate border.
// BIT-EXACT contract (verified absmax=0.0 rounds 3-7): vertical 11-tap f32 FMA
// chain (ascending row order, weight (float)(1.0/11.0)), rounded to f32; then
// horizontal 11-tap f32 FMA chain (ascending col order); thresh = m - 2.0f;
// decision x > thresh. Replicate-border mv values are bitwise duplicates of the
// edge col's chain (synthesized by duplication, never recomputed).
//
// R8 = R4 (best: 52.8us) + conflict-free column mapping.
//  - R4 mapped thread t -> cols (2t,2t+1): horizontal LDS reads mv[2t+e] put
//    lanes l and l+16 in the same bank (128B apart) -> 4-way conflict, 5.2M
//    conflict cycles. Now thread t -> cols (t, t+256): every mv read/write is
//    lane-consecutive -> zero conflicts. Arithmetic chains unchanged (bit-exact).
//  - register vertical ring (static shift), double-buffered mv, 1 barrier/row,
//    depth-1 next-row preload, RPB=32 -> 2048 blocks = 8 blocks/CU, 32 waves/CU.
//  - plain __launch_bounds__(256): R7 showed a min-waves clamp forces VGPR=64
//    and spills the ring to scratch (FETCH 106->377 MB). Never again.

constexpr int W   = 512;
constexpr int H   = 512;
constexpr int PAD = 5;            // (11-1)/2
constexpr int KS  = 11;
constexpr int TPB = 256;          // cols t and t+256 per thread
constexpr int RPB = 32;           // output rows per block
constexpr int WP  = W + 2 * PAD;  // 522 padded columns

__global__ __launch_bounds__(TPB)
void AdaptiveThresholding_57904749085171_kernel(const float* __restrict__ x,
                                                float* __restrict__ out)
{
    __shared__ float mv[2][WP];    // double-buffered vertical-pass row (4.2 KB)

    const int t  = (int)threadIdx.x;
    const int cA = t;              // first owned column
    const int cB = t + 256;        // second owned column
    const int y0 = (int)blockIdx.x * RPB;
    const size_t ioff = (size_t)blockIdx.y * (size_t)(W * H);
    const float* __restrict__ xi = x + ioff;
    float* __restrict__ oi = out + ioff;
    const float wv = (float)(1.0 / 11.0);

    // Register ring: rows y-5 .. y+5 for this thread's two columns (static idx).
    float r0[KS], r1[KS];

    // ---- prologue: virtual rows y0-5 .. y0+4 -> r[0..9] ----
    #pragma unroll
    for (int k = 0; k < KS - 1; ++k) {
        int j = y0 - PAD + k;
        int src = j < 0 ? 0 : (j >= H ? H - 1 : j);
        const float* rp = xi + (size_t)src * W;
        r0[k] = rp[cA];
        r1[k] = rp[cB];
    }
    // preload virtual row y0+5
    float p0, p1;
    {
        int j = y0 + PAD;
        int src = j >= H ? H - 1 : j;
        const float* rp = xi + (size_t)src * W;
        p0 = rp[cA];
        p1 = rp[cB];
    }

    for (int y = y0; y < y0 + RPB; ++y) {
        // complete the ring: r[d] = row y-5+d
        r0[KS - 1] = p0;
        r1[KS - 1] = p1;

        // ---- vertical f32 FMA chains (ascending row order) ----
        float a0 = 0.0f, a1 = 0.0f;
        #pragma unroll
        for (int d = 0; d < KS; ++d) {
            a0 = fmaf(r0[d], wv, a0);
            a1 = fmaf(r1[d], wv, a1);
        }

        const int pp = (y - y0) & 1;
        mv[pp][PAD + cA] = a0;                 // lanes consecutive: conflict-free
        mv[pp][PAD + cB] = a1;
        if (t == 0) {
            #pragma unroll
            for (int i = 0; i < PAD; ++i) mv[pp][i] = a0;           // == col-0 mv bitwise
        } else if (t == TPB - 1) {
            #pragma unroll
            for (int i = 0; i < PAD; ++i) mv[pp][W + PAD + i] = a1; // == col-511 mv bitwise
        }

        // center row value (row y) for the comparison, before shifting
        const float xv0 = r0[PAD];
        const float xv1 = r1[PAD];

        // ---- issue preload of next raw row (hides latency past the barrier) ----
        if (y + 1 < y0 + RPB) {
            int j = y + 1 + PAD;
            int src = j >= H ? H - 1 : j;
            const float* rp = xi + (size_t)src * W;
            p0 = rp[cA];
            p1 = rp[cB];
        }

        // ---- shift ring (static indices) ----
        #pragma unroll
        for (int d = 0; d < KS - 1; ++d) {
            r0[d] = r0[d + 1];
            r1[d] = r1[d + 1];
        }

        __syncthreads();   // mv[pp] visible to all waves

        // ---- horizontal f32 FMA chains (ascending col order) + decision ----
        // window for col c = padded idx c .. c+10; lane-consecutive reads
        float m0 = 0.0f, m1 = 0.0f;
        #pragma unroll
        for (int e = 0; e < KS; ++e) m0 = fmaf(mv[pp][cA + e], wv, m0);
        #pragma unroll
        for (int e = 0; e < KS; ++e) m1 = fmaf(mv[pp][cB + e], wv, m1);

        float* op = oi + (size_t)y * W;
        op[cA] = (xv0 > m0 - 2.0f) ? 0.0f : 255.0f;
        op[cB] = (xv1 > m1 - 2.0f) ? 0.0f : 255.0f;
        // no second barrier: next iter writes mv[pp^1]; mv[pp] is overwritten only
        // at iter y+2, after all threads pass barrier(y+1).
    }
}

extern "C" void kernel_launch(void* const* d_in, const int* in_sizes, int n_in,
                              void* d_out, int out_size, void* d_ws, size_t ws_size,
                              hipStream_t stream)
{
    const float* x = (const float*)d_in[0];
    float* out = (float*)d_out;
    const int n_imgs = in_sizes[0] / (W * H);   // 128

    dim3 grid(H / RPB, n_imgs);   // 16 x 128 = 2048 blocks
    dim3 block(TPB);
    AdaptiveThresholding_57904749085171_kernel<<<grid, block, 0, stream>>>(x, out);
}

// Round 9
// 52.035 us; speedup vs baseline: 3.4341x; 1.0624x over previous
//
#include <hip/hip_runtime.h>

// Adaptive mean thresholding: out = (x > mean11x11(x) - 2) ? 0 : 255, replicate border.
// BIT-EXACT contract (verified absmax=0.0 rounds 3-8): vertical 11-tap f32 FMA
// chain (ascending row order, weight (float)(1.0/11.0)), rounded to f32; then
// horizontal 11-tap f32 FMA chain (ascending col order); thresh = m - 2.0f;
// decision x > thresh. Replicate-border mv values are bitwise duplicates of the
// edge col's chain (synthesized by duplication, never recomputed).
//
// R9 = R8 + two-rows-per-phase:
//  - mv stored interleaved [col][rowparity] -> one ds_read_b64 per tap serves
//    BOTH rows (lane stride 8B = free 2-way aliasing); LDS instrs halve, and
//    4 independent 11-FMA chains per col give 2x ILP on the chain latency.
//  - barriers per block 32 -> 16.
//  - phase loop fully unrolled (16 phases, ring of 12, indices (2k+d)%12 all
//    compile-time) -> zero ring-shift movs (was 20 v_mov per row).
//  - NO min-waves launch bound (R7: clamping to 64 VGPR spilled the ring;
//    spill signature = FETCH 106->377 MB. Watch FETCH stays ~85 MB).

constexpr int W   = 512;
constexpr int H   = 512;
constexpr int PAD = 5;            // (11-1)/2
constexpr int KS  = 11;
constexpr int RS  = 12;           // ring slots (rows y-5 .. y+6)
constexpr int TPB = 256;          // cols t and t+256 per thread
constexpr int RPB = 32;           // output rows per block
constexpr int PH  = RPB / 2;      // 16 phases, 2 rows each
constexpr int WP  = W + 2 * PAD;  // 522 padded columns

__global__ __launch_bounds__(TPB)
void AdaptiveThresholding_57904749085171_kernel(const float* __restrict__ x,
                                                float* __restrict__ out)
{
    __shared__ float mvp[2][WP][2];   // [buf][padded col][row parity], 8.4 KB

    const int t  = (int)threadIdx.x;
    const int cA = t;
    const int cB = t + 256;
    const int y0 = (int)blockIdx.x * RPB;
    const size_t ioff = (size_t)blockIdx.y * (size_t)(W * H);
    const float* __restrict__ xi = x + ioff;
    float* __restrict__ oi = out + ioff;
    const float wv = (float)(1.0 / 11.0);

    // Ring: slot s holds virtual row v with (v - (y0-5)) mod 12 == s.
    float r0[RS], r1[RS];
    float p0a, p0b, p1a, p1b;   // preloaded next two virtual rows (cols A,B)

    // ---- prologue: virtual rows y0-5 .. y0+4 -> slots 0..9 ----
    #pragma unroll
    for (int j = 0; j < 10; ++j) {
        int v = y0 - PAD + j;
        int src = v < 0 ? 0 : (v >= H ? H - 1 : v);
        const float* rp = xi + (size_t)src * W;
        r0[j] = rp[cA];
        r1[j] = rp[cB];
    }
    {
        int v = y0 + 5;  int src = v >= H ? H - 1 : v;
        const float* rp = xi + (size_t)src * W;
        p0a = rp[cA]; p0b = rp[cB];
    }
    {
        int v = y0 + 6;  int src = v >= H ? H - 1 : v;
        const float* rp = xi + (size_t)src * W;
        p1a = rp[cA]; p1b = rp[cB];
    }

    #pragma unroll
    for (int k = 0; k < PH; ++k) {
        const int y = y0 + 2 * k;

        // ---- place preloaded rows y+5, y+6 into slots (2k+10)%12, (2k+11)%12 ----
        r0[(2 * k + 10) % RS] = p0a;  r1[(2 * k + 10) % RS] = p0b;
        r0[(2 * k + 11) % RS] = p1a;  r1[(2 * k + 11) % RS] = p1b;

        // ---- issue preload for the next phase (rows y+7, y+8, clamped) ----
        if (k + 1 < PH) {
            int v1 = y + 7;  int s1 = v1 >= H ? H - 1 : v1;
            int v2 = y + 8;  int s2 = v2 >= H ? H - 1 : v2;
            const float* rp1 = xi + (size_t)s1 * W;
            const float* rp2 = xi + (size_t)s2 * W;
            p0a = rp1[cA]; p0b = rp1[cB];
            p1a = rp2[cA]; p1b = rp2[cB];
        }

        // ---- vertical f32 FMA chains, ascending row order (4 independent) ----
        float aA0 = 0.0f, aB0 = 0.0f, aA1 = 0.0f, aB1 = 0.0f;
        #pragma unroll
        for (int d = 0; d < KS; ++d) {
            const int s = (2 * k + d) % RS;        // row y-5+d
            aA0 = fmaf(r0[s], wv, aA0);
            aB0 = fmaf(r1[s], wv, aB0);
        }
        #pragma unroll
        for (int d = 0; d < KS; ++d) {
            const int s = (2 * k + 1 + d) % RS;    // row y-4+d
            aA1 = fmaf(r0[s], wv, aA1);
            aB1 = fmaf(r1[s], wv, aB1);
        }

        const int pp = k & 1;
        *(float2*)&mvp[pp][PAD + cA][0] = make_float2(aA0, aA1);
        *(float2*)&mvp[pp][PAD + cB][0] = make_float2(aB0, aB1);
        if (t == 0) {
            #pragma unroll
            for (int i = 0; i < PAD; ++i)
                *(float2*)&mvp[pp][i][0] = make_float2(aA0, aA1);          // == col 0
        } else if (t == TPB - 1) {
            #pragma unroll
            for (int i = 0; i < PAD; ++i)
                *(float2*)&mvp[pp][W + PAD + i][0] = make_float2(aB0, aB1); // == col 511
        }

        // center values for rows y (slot 2k+5) and y+1 (slot 2k+6)
        const float xA0 = r0[(2 * k + 5) % RS], xB0 = r1[(2 * k + 5) % RS];
        const float xA1 = r0[(2 * k + 6) % RS], xB1 = r1[(2 * k + 6) % RS];

        __syncthreads();   // mvp[pp] visible; safe vs pp^1 writes (see R4/R8 note)

        // ---- horizontal f32 FMA chains (ascending col order), b64 taps ----
        float mA0 = 0.0f, mA1 = 0.0f, mB0 = 0.0f, mB1 = 0.0f;
        #pragma unroll
        for (int e = 0; e < KS; ++e) {
            const float2 v = *(const float2*)&mvp[pp][cA + e][0];
            mA0 = fmaf(v.x, wv, mA0);
            mA1 = fmaf(v.y, wv, mA1);
        }
        #pragma unroll
        for (int e = 0; e < KS; ++e) {
            const float2 v = *(const float2*)&mvp[pp][cB + e][0];
            mB0 = fmaf(v.x, wv, mB0);
            mB1 = fmaf(v.y, wv, mB1);
        }

        float* opr0 = oi + (size_t)y * W;
        float* opr1 = oi + (size_t)(y + 1) * W;
        opr0[cA] = (xA0 > mA0 - 2.0f) ? 0.0f : 255.0f;
        opr0[cB] = (xB0 > mB0 - 2.0f) ? 0.0f : 255.0f;
        opr1[cA] = (xA1 > mA1 - 2.0f) ? 0.0f : 255.0f;
        opr1[cB] = (xB1 > mB1 - 2.0f) ? 0.0f : 255.0f;
    }
}

extern "C" void kernel_launch(void* const* d_in, const int* in_sizes, int n_in,
                              void* d_out, int out_size, void* d_ws, size_t ws_size,
                              hipStream_t stream)
{
    const float* x = (const float*)d_in[0];
    float* out = (float*)d_out;
    const int n_imgs = in_sizes[0] / (W * H);   // 128

    dim3 grid(H / RPB, n_imgs);   // 16 x 128 = 2048 blocks
    dim3 block(TPB);
    AdaptiveThresholding_57904749085171_kernel<<<grid, block, 0, stream>>>(x, out);
}